// Round 8
// baseline (170.232 us; speedup 1.0000x reference)
//
#include <hip/hip_runtime.h>

typedef unsigned short u16;
typedef unsigned int u32;
typedef unsigned long long u64;
typedef __bf16 bf16x8 __attribute__((ext_vector_type(8)));
typedef float f32x4 __attribute__((ext_vector_type(4)));

union FragAB {
  bf16x8 v;
  u16 u[8];
  u32 w[4];
  u64 d2[2];
};

__device__ __forceinline__ u16 f2bf(float f) {
  u32 u = __builtin_bit_cast(u32, f);
  u += 0x7fffu + ((u >> 16) & 1u);
  return (u16)(u >> 16);
}

__device__ __forceinline__ void gload_lds16(const void* g, void* l) {
  __builtin_amdgcn_global_load_lds((__attribute__((address_space(1))) void*)g,
                                   (__attribute__((address_space(3))) void*)l, 16, 0, 0);
}

// column permutation within each 32-group: fragment for (kg) becomes 16 contiguous bytes
__device__ __forceinline__ int permcol(int n) {
  int k = n & 31;
  return (n & ~31) | ((k & 12) << 1) | ((k & 16) >> 2) | (k & 3);
}

// ---------------- fused: fp32 -> bf16 p-layout + gate logits ----------------
__global__ __launch_bounds__(256) void fused_conv_gate(const float* __restrict__ hs,
                                                       const float* __restrict__ Wg,
                                                       u16* __restrict__ out,
                                                       float* __restrict__ lgt) {
  int lane = threadIdx.x & 63, wid = threadIdx.x >> 6;
  int t = blockIdx.x * 4 + wid;
  const float* row = hs + (size_t)t * 2048;
  u16* orow = out + (size_t)t * 2048;
  float acc[8] = {0.f, 0.f, 0.f, 0.f, 0.f, 0.f, 0.f, 0.f};
#pragma unroll
  for (int j = 0; j < 8; j++) {
    int c = j * 256 + lane * 4;
    float4 v = *(const float4*)&row[c];
    u64 pk = (u64)f2bf(v.x) | ((u64)f2bf(v.y) << 16) | ((u64)f2bf(v.z) << 32) |
             ((u64)f2bf(v.w) << 48);
    int g = (c >> 2) & 7;
    int ncol = (c & ~31) | ((2 * (g & 3) + (g >> 2)) << 2);
    *(u64*)&orow[ncol] = pk;
#pragma unroll
    for (int e = 0; e < 4; e++) {
      float x = (e == 0) ? v.x : (e == 1) ? v.y : (e == 2) ? v.z : v.w;
      float4 w0 = *(const float4*)&Wg[(c + e) * 8];
      float4 w1 = *(const float4*)&Wg[(c + e) * 8 + 4];
      acc[0] += x * w0.x; acc[1] += x * w0.y; acc[2] += x * w0.z; acc[3] += x * w0.w;
      acc[4] += x * w1.x; acc[5] += x * w1.y; acc[6] += x * w1.z; acc[7] += x * w1.w;
    }
  }
#pragma unroll
  for (int h = 0; h < 8; h++) {
    float v = acc[h];
    for (int m = 1; m < 64; m <<= 1) v += __shfl_xor(v, m, 64);
    if (lane == 0) {
      float x = 6.906768f + v;
      lgt[h * 2048 + t] = -log1pf(__expf(-x));
    }
  }
}

// ---------------- transpose + convert (k-permuted), 64x64 tiles ----------------
__global__ __launch_bounds__(256) void tconv_kernel(const float* __restrict__ in,
                                                    u16* __restrict__ out, int K, int N) {
  __shared__ float tile[64][65];
  int col = threadIdx.x & 63;
  int r0 = threadIdx.x >> 6;
  int kb = blockIdx.y * 64, nb = blockIdx.x * 64;
  int pcol = permcol(col);
#pragma unroll
  for (int i = 0; i < 16; i++) {
    int r = r0 + i * 4;
    tile[r][col] = in[(size_t)(kb + r) * N + nb + col];
  }
  __syncthreads();
#pragma unroll
  for (int i = 0; i < 16; i++) {
    int r = r0 + i * 4;
    out[(size_t)(nb + r) * K + kb + pcol] = f2bf(tile[col][r]);
  }
}

// ---------------- merged weight transpose (k-permuted), 64x64 tiles ----------------
__global__ __launch_bounds__(256) void tconv3_kernel(const float* __restrict__ Wq,
                                                     const float* __restrict__ Wk,
                                                     const float* __restrict__ Wv,
                                                     u16* __restrict__ slab) {
  const int z = blockIdx.z;
  if (z > 0 && blockIdx.x >= 16) return;
  __shared__ float tile[64][65];
  const float* src = (z == 0) ? Wq : (z == 1 ? Wk : Wv);
  const int srcN = (z == 0) ? 2048 : 1024;
  const int dstRowBase = (z == 0) ? 0 : (z == 1 ? 2048 : 3072);
  int col = threadIdx.x & 63;
  int r0 = threadIdx.x >> 6;
  int kb = blockIdx.y * 64, nb = blockIdx.x * 64;
  int pcol = permcol(col);
#pragma unroll
  for (int i = 0; i < 16; i++) {
    int r = r0 + i * 4;
    tile[r][col] = src[(size_t)(kb + r) * srcN + nb + col];
  }
  __syncthreads();
#pragma unroll
  for (int i = 0; i < 16; i++) {
    int r = r0 + i * 4;
    slab[(size_t)(dstRowBase + nb + r) * 2048 + kb + pcol] = f2bf(tile[col][r]);
  }
}

// ---------------- cumsum over t per head -> gate scale table ----------------
__global__ __launch_bounds__(256) void cumsum_kernel(const float* __restrict__ lgt,
                                                     float* __restrict__ scTab) {
  int h = blockIdx.x;
  __shared__ float buf[2048];
  for (int i = threadIdx.x; i < 2048; i += 256) buf[i] = lgt[h * 2048 + i];
  __syncthreads();
  for (int off = 1; off < 2048; off <<= 1) {
    float tmp[8];
#pragma unroll
    for (int j = 0; j < 8; j++) {
      int i = threadIdx.x + j * 256;
      tmp[j] = (i >= off) ? buf[i - off] : 0.f;
    }
    __syncthreads();
#pragma unroll
    for (int j = 0; j < 8; j++) {
      int i = threadIdx.x + j * 256;
      buf[i] += tmp[j];
    }
    __syncthreads();
  }
  for (int i = threadIdx.x; i < 2048; i += 256) {
    float lg = buf[i];
    scTab[i * 16 + h] = __expf(0.5f * lg) * 0.08838834764831845f;
    scTab[i * 16 + 8 + h] = __expf(-0.5f * lg);
  }
}

// ---------------- bf16 MFMA GEMM v3: 4 waves, 64x64 per wave (32 FLOP/LDS-byte) ----------------
// MODE 1: bf16 out, permcol for n < permLim, gate-scale via scTab (qkv GEMM).
// MODE 2: split-K x2 -> f32 partials (z=0 -> C0, z=1 -> C1); grid 16*NT*2.
template <int MODE, int NT>
__global__ __launch_bounds__(256, 2) void gemm_v3(const u16* __restrict__ A,
                                                  const u16* __restrict__ BT,
                                                  void* __restrict__ C0,
                                                  void* __restrict__ C1,
                                                  const float* __restrict__ scTab,
                                                  int permLim) {
  __shared__ __align__(16) u16 As[2 * 128 * 64];
  __shared__ __align__(16) u16 Bs[2 * 128 * 64];
  constexpr int nwg = 16 * NT * (MODE == 2 ? 2 : 1);
  constexpr int cpx = nwg >> 3;
  const int raw = (int)blockIdx.x;
  const int wg = (raw & 7) * cpx + (raw >> 3);
  int bx, by, z;
  if constexpr (MODE == 2) {
    z = wg & 1;
    int t = wg >> 1;
    by = t >> 4;
    bx = t & 15;
  } else {
    z = 0;
    by = wg >> 4;
    bx = wg & 15;
  }
  const int kBeg = (MODE == 2) ? z * 1024 : 0;
  const int kEnd = (MODE == 2) ? kBeg + 1024 : 2048;
  constexpr int N = NT * 128;

  const int tid = threadIdx.x;
  const int lane = tid & 63, wid = tid >> 6;
  const int m0 = bx * 128, n0 = by * 128;
  const int wr = wid >> 1, wc = wid & 1;
  const int l15 = lane & 15, kg = lane >> 4;

  f32x4 acc[4][4];
#pragma unroll
  for (int i = 0; i < 4; i++)
#pragma unroll
    for (int j = 0; j < 4; j++) acc[i][j] = f32x4{0.f, 0.f, 0.f, 0.f};

  // staging: 1024 16B-units per matrix; each thread issues 4 per matrix.
  // LDS[row][du] = global[row][du ^ (row&7)] (p-layout source)
  int srow[4], ssu[4];
#pragma unroll
  for (int c = 0; c < 4; c++) {
    int u = (wid * 4 + c) * 64 + lane;
    srow[c] = u >> 3;
    ssu[c] = (u & 7) ^ (srow[c] & 7);
  }
  const u16* Asrc[4];
  const u16* Bsrc[4];
#pragma unroll
  for (int c = 0; c < 4; c++) {
    Asrc[c] = A + (size_t)(m0 + srow[c]) * 2048 + ssu[c] * 8;
    Bsrc[c] = BT + (size_t)(n0 + srow[c]) * 2048 + ssu[c] * 8;
  }

  auto stage = [&](int buf, int k0) {
    u16* Ad = As + buf * 8192 + (wid * 4) * 512;
    u16* Bd = Bs + buf * 8192 + (wid * 4) * 512;
#pragma unroll
    for (int c = 0; c < 4; c++) {
      gload_lds16(Asrc[c] + k0, Ad + c * 512);
      gload_lds16(Bsrc[c] + k0, Bd + c * 512);
    }
  };

  stage(0, kBeg);
  __syncthreads();

  int cur = 0;
  for (int k0 = kBeg; k0 < kEnd; k0 += 64) {
    if (k0 + 64 < kEnd) stage(cur ^ 1, k0 + 64);  // issue next tile (hidden under compute)
    const u16* Ab = As + cur * 8192;
    const u16* Bb = Bs + cur * 8192;
#pragma unroll
    for (int ks = 0; ks < 2; ks++) {
      FragAB af[4], bfr[4];
#pragma unroll
      for (int mt = 0; mt < 4; mt++) {
        int row = wr * 64 + mt * 16 + l15;
        af[mt].v = *(const bf16x8*)&Ab[row * 64 + 8 * ((ks * 4 + kg) ^ (row & 7))];
      }
#pragma unroll
      for (int nt = 0; nt < 4; nt++) {
        int row = wc * 64 + nt * 16 + l15;
        bfr[nt].v = *(const bf16x8*)&Bb[row * 64 + 8 * ((ks * 4 + kg) ^ (row & 7))];
      }
#pragma unroll
      for (int mt = 0; mt < 4; mt++)
#pragma unroll
        for (int nt = 0; nt < 4; nt++)
          acc[mt][nt] = __builtin_amdgcn_mfma_f32_16x16x32_bf16(af[mt].v, bfr[nt].v, acc[mt][nt], 0, 0, 0);
    }
    __syncthreads();  // drains staging + protects LDS reuse
    cur ^= 1;
  }

#pragma unroll
  for (int mt = 0; mt < 4; mt++) {
#pragma unroll
    for (int re = 0; re < 4; re++) {
      int m = m0 + wr * 64 + mt * 16 + kg * 4 + re;
#pragma unroll
      for (int nt = 0; nt < 4; nt++) {
        int n = n0 + wc * 64 + nt * 16 + l15;
        float v = acc[mt][nt][re];
        if constexpr (MODE == 2) {
          float* P = z ? (float*)C1 : (float*)C0;
          P[(size_t)m * N + n] = v;
        } else {
          // gate-scale: Q cols get e^{lgT/2}/sqrt(128), K cols e^{-lgS/2}, V cols 1
          int code = (n < 2048) ? (n >> 8) : ((n < 3072) ? (8 + ((n - 2048) >> 7)) : -1);
          if (code >= 0) v *= scTab[(size_t)m * 16 + code];
          int nw = (n < permLim) ? permcol(n) : n;
          ((u16*)C0)[(size_t)m * N + nw] = f2bf(v);
        }
      }
    }
  }
}

// ---------------- power attention: gates pre-folded into Q/K; norm via ones-MFMA ----------------
// QKV layout: qkv[t][4096] = [Q'perm(2048) | K'perm(1024) | Vlin(1024)]
__global__ __launch_bounds__(256, 2) void power_attn(const u16* __restrict__ QKV,
                                                     u16* __restrict__ y0b,
                                                     u16* __restrict__ y1b,
                                                     float* __restrict__ npart) {
  __shared__ __align__(16) u16 Ks[2 * 64 * 128];
  __shared__ __align__(16) u16 Vt[2 * 128 * 64];

  const int raw = (int)blockIdx.x;
  const int orig = (raw & 7) * 64 + (raw >> 3);
  const int hq = orig >> 5;
  const int j_ = orig & 31;
  const int half = j_ & 1;
  const int bslot = j_ >> 1;
  const int qa = (bslot + (hq >> 1) * 3) & 15;
  const int qt = (hq & 1) ? (15 - qa) : qa;
  const int hk = hq >> 1;
  const int t0 = qt * 128;

  const int tid = threadIdx.x, lane = tid & 63, wid = tid >> 6;
  const int l15 = lane & 15, kg = lane >> 4;
  const int l7 = l15 & 7;

  const int s4 = tid & 15, dgrp = tid >> 4;
  const int ubase = 4 * (s4 >> 3) + (s4 & 3);
  const int vhb = (s4 >> 2) & 1;

  const u16* Kbase = QKV + 2048 + hk * 128;
  const u16* Vbase = QKV + 3072 + hk * 128 + dgrp * 8;

  FragAB qf[2][4];
  int myT[2];
#pragma unroll
  for (int cg = 0; cg < 2; cg++) {
    myT[cg] = t0 + wid * 16 + cg * 64 + l15;
    const u16* qrow = QKV + (size_t)myT[cg] * 4096 + hq * 128;
#pragma unroll
    for (int ks = 0; ks < 4; ks++) qf[cg][ks].v = *(const bf16x8*)(qrow + ks * 32 + kg * 8);
  }

  FragAB ones;
#pragma unroll
  for (int i = 0; i < 8; i++) ones.u[i] = 0x3F80u;  // bf16 1.0

  f32x4 yacc[8][2];
#pragma unroll
  for (int i = 0; i < 8; i++)
#pragma unroll
    for (int c = 0; c < 2; c++) yacc[i][c] = f32x4{0.f, 0.f, 0.f, 0.f};
  f32x4 nrm[2] = {f32x4{0.f, 0.f, 0.f, 0.f}, f32x4{0.f, 0.f, 0.f, 0.f}};

  const int itBeg = half ? (qt + 1) : 0;
  const int itEnd = half ? (2 * qt + 2) : (qt + 1);

  auto stageK = [&](int s0, int bb) {
#pragma unroll
    for (int c = 0; c < 4; c++) {
      int ch = (wid * 4 + c) * 64 + lane;
      int row = ch >> 4, du = ch & 15;
      int su = du ^ (row & 7);
      gload_lds16(Kbase + (size_t)(s0 + row) * 4096 + su * 8, &Ks[bb * 8192 + (wid * 4 + c) * 512]);
    }
  };
  auto loadV = [&](int s0, uint4* vr) {
#pragma unroll
    for (int r = 0; r < 4; r++) vr[r] = *(const uint4*)(Vbase + (size_t)(s0 + 4 * s4 + r) * 4096);
  };
  auto writeV = [&](int bb, const uint4* vr) {
    u16* vd = &Vt[bb * 8192];
    const u32* w0 = (const u32*)&vr[0];
    const u32* w1 = (const u32*)&vr[1];
    const u32* w2 = (const u32*)&vr[2];
    const u32* w3 = (const u32*)&vr[3];
#pragma unroll
    for (int i = 0; i < 8; i++) {
      u32 sel = (i & 1) ? 0x07060302u : 0x05040100u;
      u32 lo = __builtin_amdgcn_perm(w1[i >> 1], w0[i >> 1], sel);
      u32 hi = __builtin_amdgcn_perm(w3[i >> 1], w2[i >> 1], sel);
      int d = dgrp * 8 + i;
      int e = d * 64 + 8 * (ubase ^ i) + 4 * vhb;
      *(u64*)&vd[e] = (u64)lo | ((u64)hi << 32);
    }
  };

  {  // prologue
    uint4 vr[4];
    stageK(itBeg * 64, 0);
    loadV(itBeg * 64, vr);
    writeV(0, vr);
  }
  __syncthreads();

  for (int it = itBeg; it < itEnd; it++) {
    const int cur = (it - itBeg) & 1;
    const int s0 = it * 64;
    const bool hasNext = (it + 1 < itEnd);
    uint4 vr[4];
    if (hasNext) {  // issue next tile's loads early (hidden under compute)
      stageK(s0 + 64, cur ^ 1);
      loadV(s0 + 64, vr);
    }

    // ---- S'^T = K' · Q'^T (gates already folded into operands) ----
    const u16* kb = &Ks[cur * 8192];
    f32x4 sacc[4][2];
#pragma unroll
    for (int mt = 0; mt < 4; mt++)
#pragma unroll
      for (int cg = 0; cg < 2; cg++) sacc[mt][cg] = f32x4{0.f, 0.f, 0.f, 0.f};
    __builtin_amdgcn_s_setprio(1);
#pragma unroll
    for (int ks = 0; ks < 4; ks++) {
#pragma unroll
      for (int mt = 0; mt < 4; mt++) {
        FragAB af;
        af.v = *(const bf16x8*)&kb[(mt * 16 + l15) * 128 + 8 * ((4 * ks + kg) ^ l7)];
        sacc[mt][0] = __builtin_amdgcn_mfma_f32_16x16x32_bf16(af.v, qf[0][ks].v, sacc[mt][0], 0, 0, 0);
        sacc[mt][1] = __builtin_amdgcn_mfma_f32_16x16x32_bf16(af.v, qf[1][ks].v, sacc[mt][1], 0, 0, 0);
      }
    }
    __builtin_amdgcn_s_setprio(0);

    // ---- P = x^2 (+ causal mask on diagonal tiles), pack to bf16 ----
    FragAB pa[2][2];
    const bool need_mask = (it >= 2 * qt);
#pragma unroll
    for (int mt = 0; mt < 4; mt++) {
#pragma unroll
      for (int cg = 0; cg < 2; cg++) {
        u32 pb[4];
#pragma unroll
        for (int r = 0; r < 4; r++) {
          float x = sacc[mt][cg][r];
          float p = x * x;
          if (need_mask) {
            int s = s0 + mt * 16 + kg * 4 + r;
            p = (s <= myT[cg]) ? p : 0.f;
          }
          pb[r] = __builtin_bit_cast(u32, p) + 0x8000u;
        }
        pa[cg][mt >> 1].w[(mt & 1) * 2 + 0] = __builtin_amdgcn_perm(pb[1], pb[0], 0x07060302u);
        pa[cg][mt >> 1].w[(mt & 1) * 2 + 1] = __builtin_amdgcn_perm(pb[3], pb[2], 0x07060302u);
      }
    }

    // ---- Y += P · V ; norm += P · 1 ----
    const u16* vb = &Vt[cur * 8192];
    const int x0 = 8 * (kg ^ l7);
    __builtin_amdgcn_s_setprio(1);
#pragma unroll
    for (int ksv = 0; ksv < 2; ksv++) {
      const int xo = x0 ^ (ksv * 32);
#pragma unroll
      for (int nt = 0; nt < 8; nt++) {
        FragAB bfv;
        bfv.v = *(const bf16x8*)&vb[(nt * 16 + l15) * 64 + xo];
        yacc[nt][0] = __builtin_amdgcn_mfma_f32_16x16x32_bf16(pa[0][ksv].v, bfv.v, yacc[nt][0], 0, 0, 0);
        yacc[nt][1] = __builtin_amdgcn_mfma_f32_16x16x32_bf16(pa[1][ksv].v, bfv.v, yacc[nt][1], 0, 0, 0);
      }
      nrm[0] = __builtin_amdgcn_mfma_f32_16x16x32_bf16(pa[0][ksv].v, ones.v, nrm[0], 0, 0, 0);
      nrm[1] = __builtin_amdgcn_mfma_f32_16x16x32_bf16(pa[1][ksv].v, ones.v, nrm[1], 0, 0, 0);
    }
    __builtin_amdgcn_s_setprio(0);

    if (hasNext) writeV(cur ^ 1, vr);
    __syncthreads();
  }

  // ---- epilogue: bf16 unnormalized partials + per-row norm partial ----
  u16* yb = half ? y1b : y0b;
  float* np = npart + half * (16 * 2048);
#pragma unroll
  for (int cg = 0; cg < 2; cg++) {
    if (l15 == 0) {
#pragma unroll
      for (int re = 0; re < 4; re++)
        np[hq * 2048 + t0 + wid * 16 + cg * 64 + kg * 4 + re] = nrm[cg][re];
    }
#pragma unroll
    for (int re = 0; re < 4; re++) {
      int trow = t0 + wid * 16 + cg * 64 + kg * 4 + re;
      u16* yrow = yb + (size_t)trow * 2048 + hq * 128;
#pragma unroll
      for (int nt = 0; nt < 8; nt++) yrow[nt * 16 + l15] = f2bf(yacc[nt][cg][re]);
    }
  }
}

// ---------------- combine 2 bf16 attention partials + normalize -> bf16 (p-layout) ----------------
__global__ __launch_bounds__(256) void combine_kernel(const u16* __restrict__ y0b,
                                                      const u16* __restrict__ y1b,
                                                      const float* __restrict__ npart,
                                                      u16* __restrict__ yb) {
  int i = blockIdx.x * 256 + threadIdx.x;
  int e0 = i << 2;
  int t = e0 >> 11;
  int hq = (e0 >> 7) & 15;
  int nidx = hq * 2048 + t;
  float nn = npart[nidx] + npart[32768 + nidx] + 1e-6f;
  float inv = 1.0f / nn;
  u64 a0 = *(const u64*)&y0b[e0];
  u64 a1 = *(const u64*)&y1b[e0];
  float r[4];
#pragma unroll
  for (int j = 0; j < 4; j++) {
    float v0 = __builtin_bit_cast(float, (u32)((a0 >> (16 * j)) & 0xffffu) << 16);
    float v1 = __builtin_bit_cast(float, (u32)((a1 >> (16 * j)) & 0xffffu) << 16);
    r[j] = (v0 + v1) * inv;
  }
  u64 pk = (u64)f2bf(r[0]) | ((u64)f2bf(r[1]) << 16) | ((u64)f2bf(r[2]) << 32) |
           ((u64)f2bf(r[3]) << 48);
  int col = e0 & 2047;
  int g = (col >> 2) & 7;
  int ncol = (col & ~31) | ((2 * (g & 3) + (g >> 2)) << 2);
  *(u64*)&yb[(size_t)t * 2048 + ncol] = pk;
}

// ---------------- combine out-GEMM split-K partials + bias (in place on d_out) ----------------
__global__ __launch_bounds__(256) void combine2_kernel(const float* __restrict__ p0,
                                                       float* __restrict__ out,
                                                       const float* __restrict__ bias) {
  int i = blockIdx.x * 256 + threadIdx.x;
  int col = (i << 2) & 2047;
  float4 a = ((const float4*)p0)[i];
  float4 b = ((const float4*)out)[i];
  float4 bb = *(const float4*)&bias[col];
  float4 r;
  r.x = a.x + b.x + bb.x;
  r.y = a.y + b.y + bb.y;
  r.z = a.z + b.z + bb.z;
  r.w = a.w + b.w + bb.w;
  ((float4*)out)[i] = r;
}

// ---------------- launch ----------------
extern "C" void kernel_launch(void* const* d_in, const int* in_sizes, int n_in,
                              void* d_out, int out_size, void* d_ws, size_t ws_size,
                              hipStream_t stream) {
  (void)in_sizes; (void)n_in; (void)out_size; (void)ws_size;
  const float* hs = (const float*)d_in[0];
  const float* Wq = (const float*)d_in[1];
  const float* Wk = (const float*)d_in[2];
  const float* Wv = (const float*)d_in[3];
  const float* Wg = (const float*)d_in[4];
  const float* Wc = (const float*)d_in[5];
  const float* bc = (const float*)d_in[6];
  float* out = (float*)d_out;

  char* ws = (char*)d_ws;
  const size_t MB = 1024 * 1024;
  u16* slab   = (u16*)(ws);
  u16* hs_bf  = (u16*)(ws + 16 * MB);
  u16* y_bf   = (u16*)(ws + 16 * MB);
  u16* qkv_bf = (u16*)(ws + 24 * MB);
  u16* y0b    = (u16*)(ws + 40 * MB);
  float* y0p  = (float*)(ws + 40 * MB);
  float* lgt   = (float*)(ws + 56 * MB);
  float* scTab = (float*)(ws + 56 * MB + 65536);
  float* npart = (float*)(ws + 56 * MB + 65536 + 131072);
  u16* y1b = (u16*)out;  // d_out as u16 scratch for half-1 partial
  u16* WcT = slab;

  fused_conv_gate<<<512, 256, 0, stream>>>(hs, Wg, hs_bf, lgt);
  cumsum_kernel<<<8, 256, 0, stream>>>(lgt, scTab);
  tconv3_kernel<<<dim3(32, 32, 3), 256, 0, stream>>>(Wq, Wk, Wv, slab);

  // merged QKV GEMM with gate-scale epilogue: [2048 x 4096] = hs_bf @ slab^T
  gemm_v3<1, 32><<<512, 256, 0, stream>>>(hs_bf, slab, qkv_bf, nullptr, scTab, 3072);

  tconv_kernel<<<dim3(32, 32), 256, 0, stream>>>(Wc, WcT, 2048, 2048);

  power_attn<<<dim3(512), 256, 0, stream>>>(qkv_bf, y0b, y1b, npart);
  combine_kernel<<<4096, 256, 0, stream>>>(y0b, y1b, npart, y_bf);

  // out GEMM split-K x2: partial0 -> y0p, partial1 -> d_out; then add + bias
  gemm_v3<2, 16><<<512, 256, 0, stream>>>(y_bf, WcT, y0p, out, nullptr, 0);
  combine2_kernel<<<4096, 256, 0, stream>>>(y0p, out, bc);
}

// Round 9
// 164.247 us; speedup vs baseline: 1.0364x; 1.0364x over previous
//
#include <hip/hip_runtime.h>

typedef unsigned short u16;
typedef unsigned int u32;
typedef unsigned long long u64;
typedef __bf16 bf16x8 __attribute__((ext_vector_type(8)));
typedef float f32x4 __attribute__((ext_vector_type(4)));

union FragAB {
  bf16x8 v;
  u16 u[8];
  u32 w[4];
  u64 d2[2];
};

__device__ __forceinline__ u16 f2bf(float f) {
  u32 u = __builtin_bit_cast(u32, f);
  u += 0x7fffu + ((u >> 16) & 1u);
  return (u16)(u >> 16);
}

__device__ __forceinline__ void gload_lds16(const void* g, void* l) {
  __builtin_amdgcn_global_load_lds((__attribute__((address_space(1))) void*)g,
                                   (__attribute__((address_space(3))) void*)l, 16, 0, 0);
}

// column permutation within each 32-group: fragment for (kg) becomes 16 contiguous bytes
__device__ __forceinline__ int permcol(int n) {
  int k = n & 31;
  return (n & ~31) | ((k & 12) << 1) | ((k & 16) >> 2) | (k & 3);
}

// ---------------- fused: fp32 -> bf16 p-layout + gate logits ----------------
__global__ __launch_bounds__(256) void fused_conv_gate(const float* __restrict__ hs,
                                                       const float* __restrict__ Wg,
                                                       u16* __restrict__ out,
                                                       float* __restrict__ lgt) {
  int lane = threadIdx.x & 63, wid = threadIdx.x >> 6;
  int t = blockIdx.x * 4 + wid;
  const float* row = hs + (size_t)t * 2048;
  u16* orow = out + (size_t)t * 2048;
  float acc[8] = {0.f, 0.f, 0.f, 0.f, 0.f, 0.f, 0.f, 0.f};
#pragma unroll
  for (int j = 0; j < 8; j++) {
    int c = j * 256 + lane * 4;
    float4 v = *(const float4*)&row[c];
    u64 pk = (u64)f2bf(v.x) | ((u64)f2bf(v.y) << 16) | ((u64)f2bf(v.z) << 32) |
             ((u64)f2bf(v.w) << 48);
    int g = (c >> 2) & 7;
    int ncol = (c & ~31) | ((2 * (g & 3) + (g >> 2)) << 2);
    *(u64*)&orow[ncol] = pk;
#pragma unroll
    for (int e = 0; e < 4; e++) {
      float x = (e == 0) ? v.x : (e == 1) ? v.y : (e == 2) ? v.z : v.w;
      float4 w0 = *(const float4*)&Wg[(c + e) * 8];
      float4 w1 = *(const float4*)&Wg[(c + e) * 8 + 4];
      acc[0] += x * w0.x; acc[1] += x * w0.y; acc[2] += x * w0.z; acc[3] += x * w0.w;
      acc[4] += x * w1.x; acc[5] += x * w1.y; acc[6] += x * w1.z; acc[7] += x * w1.w;
    }
  }
#pragma unroll
  for (int h = 0; h < 8; h++) {
    float v = acc[h];
    for (int m = 1; m < 64; m <<= 1) v += __shfl_xor(v, m, 64);
    if (lane == 0) {
      float x = 6.906768f + v;
      lgt[h * 2048 + t] = -log1pf(__expf(-x));
    }
  }
}

// ---------------- transpose + convert (k-permuted), 64x64 tiles ----------------
__global__ __launch_bounds__(256) void tconv_kernel(const float* __restrict__ in,
                                                    u16* __restrict__ out, int K, int N) {
  __shared__ float tile[64][65];
  int col = threadIdx.x & 63;
  int r0 = threadIdx.x >> 6;
  int kb = blockIdx.y * 64, nb = blockIdx.x * 64;
  int pcol = permcol(col);
#pragma unroll
  for (int i = 0; i < 16; i++) {
    int r = r0 + i * 4;
    tile[r][col] = in[(size_t)(kb + r) * N + nb + col];
  }
  __syncthreads();
#pragma unroll
  for (int i = 0; i < 16; i++) {
    int r = r0 + i * 4;
    out[(size_t)(nb + r) * K + kb + pcol] = f2bf(tile[col][r]);
  }
}

// ---------------- merged weight transpose (k-permuted), 64x64 tiles ----------------
__global__ __launch_bounds__(256) void tconv3_kernel(const float* __restrict__ Wq,
                                                     const float* __restrict__ Wk,
                                                     const float* __restrict__ Wv,
                                                     u16* __restrict__ slab) {
  const int z = blockIdx.z;
  if (z > 0 && blockIdx.x >= 16) return;
  __shared__ float tile[64][65];
  const float* src = (z == 0) ? Wq : (z == 1 ? Wk : Wv);
  const int srcN = (z == 0) ? 2048 : 1024;
  const int dstRowBase = (z == 0) ? 0 : (z == 1 ? 2048 : 3072);
  int col = threadIdx.x & 63;
  int r0 = threadIdx.x >> 6;
  int kb = blockIdx.y * 64, nb = blockIdx.x * 64;
  int pcol = permcol(col);
#pragma unroll
  for (int i = 0; i < 16; i++) {
    int r = r0 + i * 4;
    tile[r][col] = src[(size_t)(kb + r) * srcN + nb + col];
  }
  __syncthreads();
#pragma unroll
  for (int i = 0; i < 16; i++) {
    int r = r0 + i * 4;
    slab[(size_t)(dstRowBase + nb + r) * 2048 + kb + pcol] = f2bf(tile[col][r]);
  }
}

// ---------------- cumsum over t per head -> gate scale table ----------------
__global__ __launch_bounds__(256) void cumsum_kernel(const float* __restrict__ lgt,
                                                     float* __restrict__ scTab) {
  int h = blockIdx.x;
  __shared__ float buf[2048];
  for (int i = threadIdx.x; i < 2048; i += 256) buf[i] = lgt[h * 2048 + i];
  __syncthreads();
  for (int off = 1; off < 2048; off <<= 1) {
    float tmp[8];
#pragma unroll
    for (int j = 0; j < 8; j++) {
      int i = threadIdx.x + j * 256;
      tmp[j] = (i >= off) ? buf[i - off] : 0.f;
    }
    __syncthreads();
#pragma unroll
    for (int j = 0; j < 8; j++) {
      int i = threadIdx.x + j * 256;
      buf[i] += tmp[j];
    }
    __syncthreads();
  }
  for (int i = threadIdx.x; i < 2048; i += 256) {
    float lg = buf[i];
    scTab[i * 16 + h] = __expf(0.5f * lg) * 0.08838834764831845f;
    scTab[i * 16 + 8 + h] = __expf(-0.5f * lg);
  }
}

// ---------------- bf16 MFMA GEMM v4: v2 shape + counted-vmcnt pipeline (T4) ----------------
// 8 waves (512 thr), 64x32 per wave, dbuf, raw s_barrier + s_waitcnt vmcnt(4).
// MODE 1: bf16 out, permcol for n < permLim, gate-scale via scTab (qkv GEMM).
// MODE 2: split-K x2 -> f32 partials (z=0 -> C0, z=1 -> C1); grid 16*NT*2.
template <int MODE, int NT>
__global__ __launch_bounds__(512, 4) void gemm_v4(const u16* __restrict__ A,
                                                  const u16* __restrict__ BT,
                                                  void* __restrict__ C0,
                                                  void* __restrict__ C1,
                                                  const float* __restrict__ scTab,
                                                  int permLim) {
  __shared__ __align__(16) u16 As[2 * 128 * 64];
  __shared__ __align__(16) u16 Bs[2 * 128 * 64];
  constexpr int nwg = 16 * NT * (MODE == 2 ? 2 : 1);
  constexpr int cpx = nwg >> 3;
  const int raw = (int)blockIdx.x;
  const int wg = (raw & 7) * cpx + (raw >> 3);
  int bx, by, z;
  if constexpr (MODE == 2) {
    z = wg & 1;
    int t = wg >> 1;
    by = t >> 4;
    bx = t & 15;
  } else {
    z = 0;
    by = wg >> 4;
    bx = wg & 15;
  }
  const int kBeg = (MODE == 2) ? z * 1024 : 0;
  const int kEnd = (MODE == 2) ? kBeg + 1024 : 2048;
  constexpr int N = NT * 128;

  const int tid = threadIdx.x;
  const int lane = tid & 63, wid = tid >> 6;
  const int m0 = bx * 128, n0 = by * 128;
  const int wr = wid >> 2, wc = wid & 3;
  const int l15 = lane & 15, kg = lane >> 4;

  f32x4 acc[4][2];
#pragma unroll
  for (int i = 0; i < 4; i++)
#pragma unroll
    for (int j = 0; j < 2; j++) acc[i][j] = f32x4{0.f, 0.f, 0.f, 0.f};

  const int c0 = (wid * 2) * 64 + lane;
  const int c1 = c0 + 64;
  const int r0 = c0 >> 3, s0u = (c0 & 7) ^ (r0 & 7);
  const int r1 = c1 >> 3, s1u = (c1 & 7) ^ (r1 & 7);
  const u16* Asrc0 = A + (size_t)(m0 + r0) * 2048 + s0u * 8;
  const u16* Asrc1 = A + (size_t)(m0 + r1) * 2048 + s1u * 8;
  const u16* Bsrc0 = BT + (size_t)(n0 + r0) * 2048 + s0u * 8;
  const u16* Bsrc1 = BT + (size_t)(n0 + r1) * 2048 + s1u * 8;

  auto stage = [&](int buf, int k0) {
    u16* Ad = As + buf * 8192 + (wid * 2) * 512;
    u16* Bd = Bs + buf * 8192 + (wid * 2) * 512;
    gload_lds16(Asrc0 + k0, Ad);
    gload_lds16(Asrc1 + k0, Ad + 512);
    gload_lds16(Bsrc0 + k0, Bd);
    gload_lds16(Bsrc1 + k0, Bd + 512);
  };

  stage(0, kBeg);  // prologue: 4 loads in flight

  int cur = 0;
  for (int k0 = kBeg; k0 < kEnd; k0 += 64) {
    const bool hasNext = (k0 + 64 < kEnd);
    if (hasNext) {
      stage(cur ^ 1, k0 + 64);  // issue next tile's 4 loads (stay in flight across barrier)
      asm volatile("s_waitcnt vmcnt(4)" ::: "memory");  // wait ONLY the previous stage's 4
    } else {
      asm volatile("s_waitcnt vmcnt(0)" ::: "memory");
    }
    __builtin_amdgcn_sched_barrier(0);
    __builtin_amdgcn_s_barrier();  // raw barrier: no compiler vmcnt(0) drain
    __builtin_amdgcn_sched_barrier(0);

    const u16* Ab = As + cur * 8192;
    const u16* Bb = Bs + cur * 8192;
#pragma unroll
    for (int ks = 0; ks < 2; ks++) {
      FragAB af[4], bfr[2];
#pragma unroll
      for (int mt = 0; mt < 4; mt++) {
        int row = wr * 64 + mt * 16 + l15;
        af[mt].v = *(const bf16x8*)&Ab[row * 64 + 8 * ((ks * 4 + kg) ^ (row & 7))];
      }
#pragma unroll
      for (int nt = 0; nt < 2; nt++) {
        int row = wc * 32 + nt * 16 + l15;
        bfr[nt].v = *(const bf16x8*)&Bb[row * 64 + 8 * ((ks * 4 + kg) ^ (row & 7))];
      }
#pragma unroll
      for (int mt = 0; mt < 4; mt++)
#pragma unroll
        for (int nt = 0; nt < 2; nt++)
          acc[mt][nt] = __builtin_amdgcn_mfma_f32_16x16x32_bf16(af[mt].v, bfr[nt].v, acc[mt][nt], 0, 0, 0);
    }
    __builtin_amdgcn_sched_barrier(0);
    __builtin_amdgcn_s_barrier();  // all waves done reading buf[cur]; safe to re-stage next iter
    cur ^= 1;
  }

#pragma unroll
  for (int mt = 0; mt < 4; mt++) {
#pragma unroll
    for (int re = 0; re < 4; re++) {
      int m = m0 + wr * 64 + mt * 16 + kg * 4 + re;
#pragma unroll
      for (int nt = 0; nt < 2; nt++) {
        int n = n0 + wc * 32 + nt * 16 + l15;
        float v = acc[mt][nt][re];
        if constexpr (MODE == 2) {
          float* P = z ? (float*)C1 : (float*)C0;
          P[(size_t)m * N + n] = v;
        } else {
          // gate-scale: Q cols get e^{lgT/2}/sqrt(128), K cols e^{-lgS/2}, V cols 1
          int code = (n < 2048) ? (n >> 8) : ((n < 3072) ? (8 + ((n - 2048) >> 7)) : -1);
          if (code >= 0) v *= scTab[(size_t)m * 16 + code];
          int nw = (n < permLim) ? permcol(n) : n;
          ((u16*)C0)[(size_t)m * N + nw] = f2bf(v);
        }
      }
    }
  }
}

// ---------------- power attention: gates pre-folded into Q/K; norm via ones-MFMA ----------------
// QKV layout: qkv[t][4096] = [Q'perm(2048) | K'perm(1024) | Vlin(1024)]
__global__ __launch_bounds__(256, 2) void power_attn(const u16* __restrict__ QKV,
                                                     u16* __restrict__ y0b,
                                                     u16* __restrict__ y1b,
                                                     float* __restrict__ npart) {
  __shared__ __align__(16) u16 Ks[2 * 64 * 128];
  __shared__ __align__(16) u16 Vt[2 * 128 * 64];

  const int raw = (int)blockIdx.x;
  const int orig = (raw & 7) * 64 + (raw >> 3);
  const int hq = orig >> 5;
  const int j_ = orig & 31;
  const int half = j_ & 1;
  const int bslot = j_ >> 1;
  const int qa = (bslot + (hq >> 1) * 3) & 15;
  const int qt = (hq & 1) ? (15 - qa) : qa;
  const int hk = hq >> 1;
  const int t0 = qt * 128;

  const int tid = threadIdx.x, lane = tid & 63, wid = tid >> 6;
  const int l15 = lane & 15, kg = lane >> 4;
  const int l7 = l15 & 7;

  const int s4 = tid & 15, dgrp = tid >> 4;
  const int ubase = 4 * (s4 >> 3) + (s4 & 3);
  const int vhb = (s4 >> 2) & 1;

  const u16* Kbase = QKV + 2048 + hk * 128;
  const u16* Vbase = QKV + 3072 + hk * 128 + dgrp * 8;

  FragAB qf[2][4];
  int myT[2];
#pragma unroll
  for (int cg = 0; cg < 2; cg++) {
    myT[cg] = t0 + wid * 16 + cg * 64 + l15;
    const u16* qrow = QKV + (size_t)myT[cg] * 4096 + hq * 128;
#pragma unroll
    for (int ks = 0; ks < 4; ks++) qf[cg][ks].v = *(const bf16x8*)(qrow + ks * 32 + kg * 8);
  }

  FragAB ones;
#pragma unroll
  for (int i = 0; i < 8; i++) ones.u[i] = 0x3F80u;  // bf16 1.0

  f32x4 yacc[8][2];
#pragma unroll
  for (int i = 0; i < 8; i++)
#pragma unroll
    for (int c = 0; c < 2; c++) yacc[i][c] = f32x4{0.f, 0.f, 0.f, 0.f};
  f32x4 nrm[2] = {f32x4{0.f, 0.f, 0.f, 0.f}, f32x4{0.f, 0.f, 0.f, 0.f}};

  const int itBeg = half ? (qt + 1) : 0;
  const int itEnd = half ? (2 * qt + 2) : (qt + 1);

  auto stageK = [&](int s0, int bb) {
#pragma unroll
    for (int c = 0; c < 4; c++) {
      int ch = (wid * 4 + c) * 64 + lane;
      int row = ch >> 4, du = ch & 15;
      int su = du ^ (row & 7);
      gload_lds16(Kbase + (size_t)(s0 + row) * 4096 + su * 8, &Ks[bb * 8192 + (wid * 4 + c) * 512]);
    }
  };
  auto loadV = [&](int s0, uint4* vr) {
#pragma unroll
    for (int r = 0; r < 4; r++) vr[r] = *(const uint4*)(Vbase + (size_t)(s0 + 4 * s4 + r) * 4096);
  };
  auto writeV = [&](int bb, const uint4* vr) {
    u16* vd = &Vt[bb * 8192];
    const u32* w0 = (const u32*)&vr[0];
    const u32* w1 = (const u32*)&vr[1];
    const u32* w2 = (const u32*)&vr[2];
    const u32* w3 = (const u32*)&vr[3];
#pragma unroll
    for (int i = 0; i < 8; i++) {
      u32 sel = (i & 1) ? 0x07060302u : 0x05040100u;
      u32 lo = __builtin_amdgcn_perm(w1[i >> 1], w0[i >> 1], sel);
      u32 hi = __builtin_amdgcn_perm(w3[i >> 1], w2[i >> 1], sel);
      int d = dgrp * 8 + i;
      int e = d * 64 + 8 * (ubase ^ i) + 4 * vhb;
      *(u64*)&vd[e] = (u64)lo | ((u64)hi << 32);
    }
  };

  {  // prologue
    uint4 vr[4];
    stageK(itBeg * 64, 0);
    loadV(itBeg * 64, vr);
    writeV(0, vr);
  }
  __syncthreads();

  for (int it = itBeg; it < itEnd; it++) {
    const int cur = (it - itBeg) & 1;
    const int s0 = it * 64;
    const bool hasNext = (it + 1 < itEnd);
    uint4 vr[4];
    if (hasNext) {  // issue next tile's loads early (hidden under compute)
      stageK(s0 + 64, cur ^ 1);
      loadV(s0 + 64, vr);
    }

    // ---- S'^T = K' · Q'^T (gates already folded into operands) ----
    const u16* kb = &Ks[cur * 8192];
    f32x4 sacc[4][2];
#pragma unroll
    for (int mt = 0; mt < 4; mt++)
#pragma unroll
      for (int cg = 0; cg < 2; cg++) sacc[mt][cg] = f32x4{0.f, 0.f, 0.f, 0.f};
    __builtin_amdgcn_s_setprio(1);
#pragma unroll
    for (int ks = 0; ks < 4; ks++) {
#pragma unroll
      for (int mt = 0; mt < 4; mt++) {
        FragAB af;
        af.v = *(const bf16x8*)&kb[(mt * 16 + l15) * 128 + 8 * ((4 * ks + kg) ^ l7)];
        sacc[mt][0] = __builtin_amdgcn_mfma_f32_16x16x32_bf16(af.v, qf[0][ks].v, sacc[mt][0], 0, 0, 0);
        sacc[mt][1] = __builtin_amdgcn_mfma_f32_16x16x32_bf16(af.v, qf[1][ks].v, sacc[mt][1], 0, 0, 0);
      }
    }
    __builtin_amdgcn_s_setprio(0);

    // ---- P = x^2 (+ causal mask on diagonal tiles), pack to bf16 ----
    FragAB pa[2][2];
    const bool need_mask = (it >= 2 * qt);
#pragma unroll
    for (int mt = 0; mt < 4; mt++) {
#pragma unroll
      for (int cg = 0; cg < 2; cg++) {
        u32 pb[4];
#pragma unroll
        for (int r = 0; r < 4; r++) {
          float x = sacc[mt][cg][r];
          float p = x * x;
          if (need_mask) {
            int s = s0 + mt * 16 + kg * 4 + r;
            p = (s <= myT[cg]) ? p : 0.f;
          }
          pb[r] = __builtin_bit_cast(u32, p) + 0x8000u;
        }
        pa[cg][mt >> 1].w[(mt & 1) * 2 + 0] = __builtin_amdgcn_perm(pb[1], pb[0], 0x07060302u);
        pa[cg][mt >> 1].w[(mt & 1) * 2 + 1] = __builtin_amdgcn_perm(pb[3], pb[2], 0x07060302u);
      }
    }

    // ---- Y += P · V ; norm += P · 1 ----
    const u16* vb = &Vt[cur * 8192];
    const int x0 = 8 * (kg ^ l7);
    __builtin_amdgcn_s_setprio(1);
#pragma unroll
    for (int ksv = 0; ksv < 2; ksv++) {
      const int xo = x0 ^ (ksv * 32);
#pragma unroll
      for (int nt = 0; nt < 8; nt++) {
        FragAB bfv;
        bfv.v = *(const bf16x8*)&vb[(nt * 16 + l15) * 64 + xo];
        yacc[nt][0] = __builtin_amdgcn_mfma_f32_16x16x32_bf16(pa[0][ksv].v, bfv.v, yacc[nt][0], 0, 0, 0);
        yacc[nt][1] = __builtin_amdgcn_mfma_f32_16x16x32_bf16(pa[1][ksv].v, bfv.v, yacc[nt][1], 0, 0, 0);
      }
      nrm[0] = __builtin_amdgcn_mfma_f32_16x16x32_bf16(pa[0][ksv].v, ones.v, nrm[0], 0, 0, 0);
      nrm[1] = __builtin_amdgcn_mfma_f32_16x16x32_bf16(pa[1][ksv].v, ones.v, nrm[1], 0, 0, 0);
    }
    __builtin_amdgcn_s_setprio(0);

    if (hasNext) writeV(cur ^ 1, vr);
    __syncthreads();
  }

  // ---- epilogue: bf16 unnormalized partials + per-row norm partial ----
  u16* yb = half ? y1b : y0b;
  float* np = npart + half * (16 * 2048);
#pragma unroll
  for (int cg = 0; cg < 2; cg++) {
    if (l15 == 0) {
#pragma unroll
      for (int re = 0; re < 4; re++)
        np[hq * 2048 + t0 + wid * 16 + cg * 64 + kg * 4 + re] = nrm[cg][re];
    }
#pragma unroll
    for (int re = 0; re < 4; re++) {
      int trow = t0 + wid * 16 + cg * 64 + kg * 4 + re;
      u16* yrow = yb + (size_t)trow * 2048 + hq * 128;
#pragma unroll
      for (int nt = 0; nt < 8; nt++) yrow[nt * 16 + l15] = f2bf(yacc[nt][cg][re]);
    }
  }
}

// ---------------- combine 2 bf16 attention partials + normalize -> bf16 (p-layout) ----------------
__global__ __launch_bounds__(256) void combine_kernel(const u16* __restrict__ y0b,
                                                      const u16* __restrict__ y1b,
                                                      const float* __restrict__ npart,
                                                      u16* __restrict__ yb) {
  int i = blockIdx.x * 256 + threadIdx.x;
  int e0 = i << 2;
  int t = e0 >> 11;
  int hq = (e0 >> 7) & 15;
  int nidx = hq * 2048 + t;
  float nn = npart[nidx] + npart[32768 + nidx] + 1e-6f;
  float inv = 1.0f / nn;
  u64 a0 = *(const u64*)&y0b[e0];
  u64 a1 = *(const u64*)&y1b[e0];
  float r[4];
#pragma unroll
  for (int j = 0; j < 4; j++) {
    float v0 = __builtin_bit_cast(float, (u32)((a0 >> (16 * j)) & 0xffffu) << 16);
    float v1 = __builtin_bit_cast(float, (u32)((a1 >> (16 * j)) & 0xffffu) << 16);
    r[j] = (v0 + v1) * inv;
  }
  u64 pk = (u64)f2bf(r[0]) | ((u64)f2bf(r[1]) << 16) | ((u64)f2bf(r[2]) << 32) |
           ((u64)f2bf(r[3]) << 48);
  int col = e0 & 2047;
  int g = (col >> 2) & 7;
  int ncol = (col & ~31) | ((2 * (g & 3) + (g >> 2)) << 2);
  *(u64*)&yb[(size_t)t * 2048 + ncol] = pk;
}

// ---------------- combine out-GEMM split-K partials + bias (in place on d_out) ----------------
__global__ __launch_bounds__(256) void combine2_kernel(const float* __restrict__ p0,
                                                       float* __restrict__ out,
                                                       const float* __restrict__ bias) {
  int i = blockIdx.x * 256 + threadIdx.x;
  int col = (i << 2) & 2047;
  float4 a = ((const float4*)p0)[i];
  float4 b = ((const float4*)out)[i];
  float4 bb = *(const float4*)&bias[col];
  float4 r;
  r.x = a.x + b.x + bb.x;
  r.y = a.y + b.y + bb.y;
  r.z = a.z + b.z + bb.z;
  r.w = a.w + b.w + bb.w;
  ((float4*)out)[i] = r;
}

// ---------------- launch ----------------
extern "C" void kernel_launch(void* const* d_in, const int* in_sizes, int n_in,
                              void* d_out, int out_size, void* d_ws, size_t ws_size,
                              hipStream_t stream) {
  (void)in_sizes; (void)n_in; (void)out_size; (void)ws_size;
  const float* hs = (const float*)d_in[0];
  const float* Wq = (const float*)d_in[1];
  const float* Wk = (const float*)d_in[2];
  const float* Wv = (const float*)d_in[3];
  const float* Wg = (const float*)d_in[4];
  const float* Wc = (const float*)d_in[5];
  const float* bc = (const float*)d_in[6];
  float* out = (float*)d_out;

  char* ws = (char*)d_ws;
  const size_t MB = 1024 * 1024;
  u16* slab   = (u16*)(ws);
  u16* hs_bf  = (u16*)(ws + 16 * MB);
  u16* y_bf   = (u16*)(ws + 16 * MB);
  u16* qkv_bf = (u16*)(ws + 24 * MB);
  u16* y0b    = (u16*)(ws + 40 * MB);
  float* y0p  = (float*)(ws + 40 * MB);
  float* lgt   = (float*)(ws + 56 * MB);
  float* scTab = (float*)(ws + 56 * MB + 65536);
  float* npart = (float*)(ws + 56 * MB + 65536 + 131072);
  u16* y1b = (u16*)out;  // d_out as u16 scratch for half-1 partial
  u16* WcT = slab;

  fused_conv_gate<<<512, 256, 0, stream>>>(hs, Wg, hs_bf, lgt);
  cumsum_kernel<<<8, 256, 0, stream>>>(lgt, scTab);
  tconv3_kernel<<<dim3(32, 32, 3), 256, 0, stream>>>(Wq, Wk, Wv, slab);

  // merged QKV GEMM with gate-scale epilogue: [2048 x 4096] = hs_bf @ slab^T
  gemm_v4<1, 32><<<512, 512, 0, stream>>>(hs_bf, slab, qkv_bf, nullptr, scTab, 3072);

  tconv_kernel<<<dim3(32, 32), 256, 0, stream>>>(Wc, WcT, 2048, 2048);

  power_attn<<<dim3(512), 256, 0, stream>>>(qkv_bf, y0b, y1b, npart);
  combine_kernel<<<4096, 256, 0, stream>>>(y0b, y1b, npart, y_bf);

  // out GEMM split-K x2: partial0 -> y0p, partial1 -> d_out; then add + bias
  gemm_v4<2, 16><<<512, 512, 0, stream>>>(y_bf, WcT, y0p, out, nullptr, 0);
  combine2_kernel<<<4096, 256, 0, stream>>>(y0p, out, bc);
}